// Round 2
// baseline (509.895 us; speedup 1.0000x reference)
//
#include <hip/hip_runtime.h>
#include <math.h>

#define DIM 1024
#define HID 64
#define SD  32
#define NS  64
#define TM  128
#define BK  32
#define LRc 0.01f
#define EPSc 1e-8f

// ---------------- zero the global accumulator (64 x 33 floats) ----------------
__global__ __launch_bounds__(256) void zero_acc_kernel(float* __restrict__ gacc) {
    int i = blockIdx.x * 256 + threadIdx.x;
    if (i < NS * (SD + 1)) gacc[i] = 0.0f;
}

// ---------------- main fused kernel: GEMM1 + encode + argmax + scatter ----------------
__global__ __launch_bounds__(256, 2) void neo_main_kernel(
    const float* __restrict__ traces, const float* __restrict__ W1,
    const float* __restrict__ b1,     const float* __restrict__ W2,
    const float* __restrict__ b2,     const float* __restrict__ schemas,
    float* __restrict__ gacc)
{
    // union: GEMM staging buffers vs epilogue buffers (disjoint lifetimes)
    union Smem {
        struct { float Als[BK][TM + 4]; float Bls[BK][HID]; } g;   // 16896 + 8192
        struct { float hs[TM][HID + 1]; float es[TM][SD + 1]; } e; // 33280 + 16896
    };
    __shared__ Smem u;
    __shared__ float W2ls[HID][SD + 4];   // padded to 36 floats/row (16B aligned)
    __shared__ float Sn[NS][SD];          // normalized schemas
    __shared__ float accl[NS][SD + 1];    // block-local sums + count

    const int t = threadIdx.x;

    // ---- stage W2 into LDS ----
    for (int i = t; i < HID * SD; i += 256)
        W2ls[i / SD][i % SD] = W2[i];

    // ---- normalized schemas ----
    if (t < NS) {
        float v[SD];
        float ss = 0.0f;
        #pragma unroll
        for (int c = 0; c < SD; ++c) { v[c] = schemas[t * SD + c]; ss += v[c] * v[c]; }
        float sc = 1.0f / fmaxf(sqrtf(ss), EPSc);
        #pragma unroll
        for (int c = 0; c < SD; ++c) Sn[t][c] = v[c] * sc;
    }

    // ---- zero block-local accumulator ----
    for (int i = t; i < NS * (SD + 1); i += 256)
        (&accl[0][0])[i] = 0.0f;

    // ---- GEMM1: (128 x 1024) @ (1024 x 64) ----
    const int rg = t >> 4;      // row group 0..15  -> rows rg*8 .. rg*8+7
    const int cg = t & 15;      // col group 0..15  -> cols cg*4 .. cg*4+3
    const long rowbase = (long)blockIdx.x * TM;

    float acc[8][4];
    #pragma unroll
    for (int i = 0; i < 8; ++i)
        #pragma unroll
        for (int j = 0; j < 4; ++j) acc[i][j] = 0.0f;

    for (int kc = 0; kc < DIM; kc += BK) {
        __syncthreads();   // protect LDS from previous iter's readers

        // stage A tile transposed: Als[k][r]  (k-major, conflict-free b128 reads)
        #pragma unroll
        for (int i = 0; i < 4; ++i) {
            int s = t + i * 256;          // 0..1023
            int r  = s >> 3;              // 0..127
            int kv = s & 7;               // 0..7  -> cols kv*4..kv*4+3
            const float4 v = *(const float4*)(traces + (rowbase + r) * DIM + kc + kv * 4);
            u.g.Als[kv * 4 + 0][r] = v.x;
            u.g.Als[kv * 4 + 1][r] = v.y;
            u.g.Als[kv * 4 + 2][r] = v.z;
            u.g.Als[kv * 4 + 3][r] = v.w;
        }
        // stage B tile (W1 rows kc..kc+31)
        #pragma unroll
        for (int i = 0; i < 2; ++i) {
            int s = t + i * 256;          // 0..511
            int kk = s >> 4;              // 0..31
            int cv = s & 15;              // 0..15
            const float4 v = *(const float4*)(W1 + (long)(kc + kk) * HID + cv * 4);
            *(float4*)&u.g.Bls[kk][cv * 4] = v;
        }
        __syncthreads();

        #pragma unroll
        for (int kk = 0; kk < BK; ++kk) {
            float4 a0 = *(const float4*)&u.g.Als[kk][rg * 8];
            float4 a1 = *(const float4*)&u.g.Als[kk][rg * 8 + 4];
            float4 bv = *(const float4*)&u.g.Bls[kk][cg * 4];
            float a[8] = {a0.x, a0.y, a0.z, a0.w, a1.x, a1.y, a1.z, a1.w};
            float b[4] = {bv.x, bv.y, bv.z, bv.w};
            #pragma unroll
            for (int i = 0; i < 8; ++i)
                #pragma unroll
                for (int j = 0; j < 4; ++j)
                    acc[i][j] = fmaf(a[i], b[j], acc[i][j]);
        }
    }
    __syncthreads();   // GEMM staging buffers now dead; union flips to epilogue

    // ---- h = relu(acc + b1) into LDS ----
    {
        float bb[4];
        #pragma unroll
        for (int j = 0; j < 4; ++j) bb[j] = b1[cg * 4 + j];
        #pragma unroll
        for (int i = 0; i < 8; ++i)
            #pragma unroll
            for (int j = 0; j < 4; ++j)
                u.e.hs[rg * 8 + i][cg * 4 + j] = fmaxf(acc[i][j] + bb[j], 0.0f);
    }
    __syncthreads();

    // ---- encoded = h @ W2 + b2 : thread handles (row r, 16-col half) ----
    {
        const int r = t >> 1;
        const int half = t & 1;
        const int c0 = half * 16;
        float enc[16];
        #pragma unroll
        for (int j = 0; j < 16; ++j) enc[j] = 0.0f;
        for (int k = 0; k < HID; ++k) {
            float hk = u.e.hs[r][k];
            #pragma unroll
            for (int c4 = 0; c4 < 4; ++c4) {
                float4 w = *(const float4*)&W2ls[k][c0 + c4 * 4];
                enc[c4 * 4 + 0] = fmaf(hk, w.x, enc[c4 * 4 + 0]);
                enc[c4 * 4 + 1] = fmaf(hk, w.y, enc[c4 * 4 + 1]);
                enc[c4 * 4 + 2] = fmaf(hk, w.z, enc[c4 * 4 + 2]);
                enc[c4 * 4 + 3] = fmaf(hk, w.w, enc[c4 * 4 + 3]);
            }
        }
        #pragma unroll
        for (int j = 0; j < 16; ++j) {
            enc[j] += b2[c0 + j];
            u.e.es[r][c0 + j] = enc[j];
        }
    }
    __syncthreads();

    // ---- sims + argmax + block-local scatter (one thread per row) ----
    if (t < TM) {
        float e[SD];
        #pragma unroll
        for (int c = 0; c < SD; ++c) e[c] = u.e.es[t][c];

        // argmax over schemas; per-row positive normalization can't change argmax -> skip it
        float best = -INFINITY;
        int bi = 0;
        for (int s = 0; s < NS; ++s) {
            float d = 0.0f;
            #pragma unroll
            for (int c4 = 0; c4 < 8; ++c4) {
                float4 sv = *(const float4*)&Sn[s][c4 * 4];
                d = fmaf(e[c4 * 4 + 0], sv.x, d);
                d = fmaf(e[c4 * 4 + 1], sv.y, d);
                d = fmaf(e[c4 * 4 + 2], sv.z, d);
                d = fmaf(e[c4 * 4 + 3], sv.w, d);
            }
            if (d > best) { best = d; bi = s; }   // strict > keeps first max (jnp semantics)
        }
        atomicAdd(&accl[bi][SD], 1.0f);
        #pragma unroll
        for (int c = 0; c < SD; ++c) atomicAdd(&accl[bi][c], e[c]);
    }
    __syncthreads();

    // ---- flush block partials to global accumulator ----
    for (int i = t; i < NS * (SD + 1); i += 256)
        atomicAdd(&gacc[i], (&accl[0][0])[i]);
}

// ---------------- finalize: schema update + stats ----------------
__global__ __launch_bounds__(64) void neo_finalize_kernel(
    const float* __restrict__ gacc, const float* __restrict__ schemas,
    const float* __restrict__ usage, float* __restrict__ out)
{
    const int s = threadIdx.x;   // 64 threads, 1 wave
    float count = gacc[s * (SD + 1) + SD];
    bool  ne    = count > 0.0f;
    float invc  = 1.0f / fmaxf(count, 1.0f);

    float nsq = 0.0f;
    #pragma unroll
    for (int c = 0; c < SD; ++c) {
        float sum    = gacc[s * (SD + 1) + c];
        float sch    = schemas[s * SD + c];
        float target = sum * invc;
        float delta  = ne ? (LRc * (target - sch)) : 0.0f;
        out[s * SD + c] = sch + delta;
        nsq = fmaf(delta, delta, nsq);
    }
    out[NS * SD + s] = usage[s] + count;

    float nrm = sqrtf(nsq);
    int nu = ne ? 1 : 0;
    #pragma unroll
    for (int off = 32; off > 0; off >>= 1) {
        nrm += __shfl_down(nrm, off);
        nu  += __shfl_down(nu, off);
    }
    if (s == 0) {
        out[NS * SD + NS]     = (float)nu;
        out[NS * SD + NS + 1] = nrm / (float)(nu > 0 ? nu : 1);
    }
}

extern "C" void kernel_launch(void* const* d_in, const int* in_sizes, int n_in,
                              void* d_out, int out_size, void* d_ws, size_t ws_size,
                              hipStream_t stream) {
    const float* traces  = (const float*)d_in[0];
    const float* W1      = (const float*)d_in[1];
    const float* b1      = (const float*)d_in[2];
    const float* W2      = (const float*)d_in[3];
    const float* b2      = (const float*)d_in[4];
    const float* schemas = (const float*)d_in[5];
    const float* usage   = (const float*)d_in[6];
    float* out  = (float*)d_out;
    float* gacc = (float*)d_ws;   // 64*33 floats

    const int N = in_sizes[0] / DIM;
    const int nblk = N / TM;

    // 2112 floats -> 9 blocks of 256 (round-1 fix: grid=1 left 0xAA poison in
    // slots >=256, which then ACCUMULATED across graph replays)
    hipLaunchKernelGGL(zero_acc_kernel, dim3((NS * (SD + 1) + 255) / 256), dim3(256), 0, stream, gacc);
    hipLaunchKernelGGL(neo_main_kernel, dim3(nblk), dim3(256), 0, stream,
                       traces, W1, b1, W2, b2, schemas, gacc);
    hipLaunchKernelGGL(neo_finalize_kernel, dim3(1), dim3(64), 0, stream,
                       gacc, schemas, usage, out);
}

// Round 3
// 172.642 us; speedup vs baseline: 2.9535x; 2.9535x over previous
//
#include <hip/hip_runtime.h>
#include <hip/hip_bf16.h>
#include <math.h>

#define DIM 1024
#define HID 64
#define SD  32
#define NS  64
#define TM  128
#define LRc 0.01f
#define EPSc 1e-8f

typedef __attribute__((ext_vector_type(8))) short bf16x8;
typedef __attribute__((ext_vector_type(4))) float f32x4;

__device__ __forceinline__ unsigned short f2bf(float f) {
    union { __hip_bfloat16 h; unsigned short u; } cv;
    cv.h = __float2bfloat16(f);
    return cv.u;
}
__device__ __forceinline__ float bf2f(unsigned short u) {
    union { unsigned short u; __hip_bfloat16 h; } cv;
    cv.u = u;
    return __bfloat162float(cv.h);
}

// ---------------- zero the global accumulator (64 x 33 floats) ----------------
__global__ __launch_bounds__(256) void zero_acc_kernel(float* __restrict__ gacc) {
    int i = blockIdx.x * 256 + threadIdx.x;
    if (i < NS * (SD + 1)) gacc[i] = 0.0f;
}

// ---------------- pack W1 -> bf16 hi/lo, MFMA-fragment order ----------------
// frag (kb, n): lane l, elem j  ->  W1[kb*32 + (l>>4)*8 + j][n*16 + (l&15)]
// stored lane-linear: idx = ((kb*4 + n)*64 + l)*8 + j   (each lane's 8 elems = 16B)
__global__ __launch_bounds__(256) void pack_w1_kernel(const float* __restrict__ W1,
                                                      unsigned short* __restrict__ W1h,
                                                      unsigned short* __restrict__ W1l) {
    int idx = blockIdx.x * 256 + threadIdx.x;   // 0..65535
    int j  = idx & 7;
    int l  = (idx >> 3) & 63;
    int n  = (idx >> 9) & 3;
    int kb = idx >> 11;
    int k  = kb * 32 + (l >> 4) * 8 + j;
    int c  = n * 16 + (l & 15);
    float w = W1[k * HID + c];
    unsigned short hu = f2bf(w);
    W1h[idx] = hu;
    W1l[idx] = f2bf(w - bf2f(hu));
}

struct StepBuf {
    float4 a[2][2];        // [row-frag m][k-half]
    bf16x8 bh[4], bl[4];   // [col-frag n]
};

__device__ __forceinline__ void load_step(StepBuf& s,
                                          const float* __restrict__ A0p, const float* __restrict__ A1p,
                                          const unsigned short* __restrict__ W1h,
                                          const unsigned short* __restrict__ W1l,
                                          int kb, int l) {
    const int K0 = kb * 32;
    s.a[0][0] = *(const float4*)(A0p + K0);
    s.a[0][1] = *(const float4*)(A0p + K0 + 4);
    s.a[1][0] = *(const float4*)(A1p + K0);
    s.a[1][1] = *(const float4*)(A1p + K0 + 4);
    const size_t fb = (size_t)kb * 2048 + (size_t)l * 8;  // (kb*4+n)*512 + l*8
    #pragma unroll
    for (int n = 0; n < 4; ++n) {
        s.bh[n] = *(const bf16x8*)(W1h + fb + (size_t)n * 512);
        s.bl[n] = *(const bf16x8*)(W1l + fb + (size_t)n * 512);
    }
}

__device__ __forceinline__ void cvt_split(const float4 a, const float4 b, bf16x8& hi, bf16x8& lo) {
    float f[8] = {a.x, a.y, a.z, a.w, b.x, b.y, b.z, b.w};
    #pragma unroll
    for (int j = 0; j < 8; ++j) {
        unsigned short hu = f2bf(f[j]);
        hi[j] = (short)hu;
        lo[j] = (short)f2bf(f[j] - bf2f(hu));
    }
}

__device__ __forceinline__ void comp_step(const StepBuf& s, f32x4 (&acc)[2][4]) {
    bf16x8 ah[2], al[2];
    #pragma unroll
    for (int m = 0; m < 2; ++m) cvt_split(s.a[m][0], s.a[m][1], ah[m], al[m]);
    #pragma unroll
    for (int m = 0; m < 2; ++m)
        #pragma unroll
        for (int n = 0; n < 4; ++n) {
            acc[m][n] = __builtin_amdgcn_mfma_f32_16x16x32_bf16(ah[m], s.bh[n], acc[m][n], 0, 0, 0);
            acc[m][n] = __builtin_amdgcn_mfma_f32_16x16x32_bf16(al[m], s.bh[n], acc[m][n], 0, 0, 0);
            acc[m][n] = __builtin_amdgcn_mfma_f32_16x16x32_bf16(ah[m], s.bl[n], acc[m][n], 0, 0, 0);
        }
}

// ---------------- main fused kernel: MFMA GEMM1 + encode + argmax + scatter ----------------
__global__ __launch_bounds__(256, 2) void neo_main_kernel(
    const float* __restrict__ traces,
    const unsigned short* __restrict__ W1h, const unsigned short* __restrict__ W1l,
    const float* __restrict__ b1,     const float* __restrict__ W2,
    const float* __restrict__ b2,     const float* __restrict__ schemas,
    float* __restrict__ gacc)
{
    __shared__ float hs[TM][HID + 1];     // 33280 B
    __shared__ float es[TM][SD + 1];      // 16896 B
    __shared__ float W2ls[HID][SD + 4];   //  9216 B
    __shared__ float Sn[NS][SD];          //  8192 B
    __shared__ float accl[NS][SD + 1];    //  8448 B

    const int t  = threadIdx.x;
    const int l  = t & 63;
    const int wq = t >> 6;       // wave id 0..3 -> rows wq*32..wq*32+31
    const int lr = l & 15;       // row-in-frag (A) / col-in-frag (B,C)
    const int lg = l >> 4;       // k-group / C row-group

    // ---- stage W2 into LDS ----
    for (int i = t; i < HID * SD; i += 256)
        W2ls[i / SD][i % SD] = W2[i];

    // ---- normalized schemas ----
    if (t < NS) {
        float v[SD];
        float ss = 0.0f;
        #pragma unroll
        for (int c = 0; c < SD; ++c) { v[c] = schemas[t * SD + c]; ss += v[c] * v[c]; }
        float sc = 1.0f / fmaxf(sqrtf(ss), EPSc);
        #pragma unroll
        for (int c = 0; c < SD; ++c) Sn[t][c] = v[c] * sc;
    }

    // ---- zero block-local accumulator ----
    for (int i = t; i < NS * (SD + 1); i += 256)
        (&accl[0][0])[i] = 0.0f;

    // ---- GEMM1 via split-bf16 MFMA: (128 x 1024) @ (1024 x 64) ----
    const float* A0p = traces + (size_t)(blockIdx.x * TM + wq * 32 + lr) * DIM + lg * 8;
    const float* A1p = A0p + (size_t)16 * DIM;

    f32x4 acc[2][4];
    #pragma unroll
    for (int m = 0; m < 2; ++m)
        #pragma unroll
        for (int n = 0; n < 4; ++n) acc[m][n] = (f32x4){0.f, 0.f, 0.f, 0.f};

    StepBuf s0, s1;
    load_step(s0, A0p, A1p, W1h, W1l, 0, l);
    for (int kb = 0; kb < 32; kb += 2) {
        load_step(s1, A0p, A1p, W1h, W1l, kb + 1, l);
        comp_step(s0, acc);
        if (kb + 2 < 32) load_step(s0, A0p, A1p, W1h, W1l, kb + 2, l);
        comp_step(s1, acc);
    }

    // ---- h = relu(acc + b1) into LDS (MFMA C-layout: row=(l>>4)*4+r, col=n*16+(l&15)) ----
    {
        float b1v[4];
        #pragma unroll
        for (int n = 0; n < 4; ++n) b1v[n] = b1[n * 16 + lr];
        #pragma unroll
        for (int m = 0; m < 2; ++m)
            #pragma unroll
            for (int n = 0; n < 4; ++n)
                #pragma unroll
                for (int r = 0; r < 4; ++r) {
                    int row = wq * 32 + m * 16 + lg * 4 + r;
                    hs[row][n * 16 + lr] = fmaxf(acc[m][n][r] + b1v[n], 0.0f);
                }
    }
    __syncthreads();

    // ---- encoded = h @ W2 + b2 : thread handles (row r, 16-col half) ----
    {
        const int r = t >> 1;
        const int half = t & 1;
        const int c0 = half * 16;
        float enc[16];
        #pragma unroll
        for (int j = 0; j < 16; ++j) enc[j] = 0.0f;
        for (int k = 0; k < HID; ++k) {
            float hk = hs[r][k];
            #pragma unroll
            for (int c4 = 0; c4 < 4; ++c4) {
                float4 w = *(const float4*)&W2ls[k][c0 + c4 * 4];
                enc[c4 * 4 + 0] = fmaf(hk, w.x, enc[c4 * 4 + 0]);
                enc[c4 * 4 + 1] = fmaf(hk, w.y, enc[c4 * 4 + 1]);
                enc[c4 * 4 + 2] = fmaf(hk, w.z, enc[c4 * 4 + 2]);
                enc[c4 * 4 + 3] = fmaf(hk, w.w, enc[c4 * 4 + 3]);
            }
        }
        #pragma unroll
        for (int j = 0; j < 16; ++j) {
            enc[j] += b2[c0 + j];
            es[r][c0 + j] = enc[j];
        }
    }
    __syncthreads();

    // ---- sims + argmax + block-local scatter (one thread per row) ----
    if (t < TM) {
        float e[SD];
        #pragma unroll
        for (int c = 0; c < SD; ++c) e[c] = es[t][c];

        // per-row positive normalization can't change argmax -> skip it
        float best = -INFINITY;
        int bi = 0;
        for (int s = 0; s < NS; ++s) {
            float d = 0.0f;
            #pragma unroll
            for (int c4 = 0; c4 < 8; ++c4) {
                float4 sv = *(const float4*)&Sn[s][c4 * 4];
                d = fmaf(e[c4 * 4 + 0], sv.x, d);
                d = fmaf(e[c4 * 4 + 1], sv.y, d);
                d = fmaf(e[c4 * 4 + 2], sv.z, d);
                d = fmaf(e[c4 * 4 + 3], sv.w, d);
            }
            if (d > best) { best = d; bi = s; }   // strict > keeps first max (jnp semantics)
        }
        atomicAdd(&accl[bi][SD], 1.0f);
        #pragma unroll
        for (int c = 0; c < SD; ++c) atomicAdd(&accl[bi][c], e[c]);
    }
    __syncthreads();

    // ---- flush block partials to global accumulator ----
    for (int i = t; i < NS * (SD + 1); i += 256)
        atomicAdd(&gacc[i], (&accl[0][0])[i]);
}

// ---------------- finalize: schema update + stats ----------------
__global__ __launch_bounds__(64) void neo_finalize_kernel(
    const float* __restrict__ gacc, const float* __restrict__ schemas,
    const float* __restrict__ usage, float* __restrict__ out)
{
    const int s = threadIdx.x;   // 64 threads, 1 wave
    float count = gacc[s * (SD + 1) + SD];
    bool  ne    = count > 0.0f;
    float invc  = 1.0f / fmaxf(count, 1.0f);

    float nsq = 0.0f;
    #pragma unroll
    for (int c = 0; c < SD; ++c) {
        float sum    = gacc[s * (SD + 1) + c];
        float sch    = schemas[s * SD + c];
        float target = sum * invc;
        float delta  = ne ? (LRc * (target - sch)) : 0.0f;
        out[s * SD + c] = sch + delta;
        nsq = fmaf(delta, delta, nsq);
    }
    out[NS * SD + s] = usage[s] + count;

    float nrm = sqrtf(nsq);
    int nu = ne ? 1 : 0;
    #pragma unroll
    for (int off = 32; off > 0; off >>= 1) {
        nrm += __shfl_down(nrm, off);
        nu  += __shfl_down(nu, off);
    }
    if (s == 0) {
        out[NS * SD + NS]     = (float)nu;
        out[NS * SD + NS + 1] = nrm / (float)(nu > 0 ? nu : 1);
    }
}

extern "C" void kernel_launch(void* const* d_in, const int* in_sizes, int n_in,
                              void* d_out, int out_size, void* d_ws, size_t ws_size,
                              hipStream_t stream) {
    const float* traces  = (const float*)d_in[0];
    const float* W1      = (const float*)d_in[1];
    const float* b1      = (const float*)d_in[2];
    const float* W2      = (const float*)d_in[3];
    const float* b2      = (const float*)d_in[4];
    const float* schemas = (const float*)d_in[5];
    const float* usage   = (const float*)d_in[6];
    float* out  = (float*)d_out;

    float* gacc = (float*)d_ws;                                        // 8448 B
    unsigned short* W1h = (unsigned short*)((char*)d_ws + 16384);      // 128 KB
    unsigned short* W1l = (unsigned short*)((char*)d_ws + 16384 + 131072);

    const int N = in_sizes[0] / DIM;
    const int nblk = N / TM;

    hipLaunchKernelGGL(pack_w1_kernel, dim3(DIM * HID / 256), dim3(256), 0, stream, W1, W1h, W1l);
    hipLaunchKernelGGL(zero_acc_kernel, dim3((NS * (SD + 1) + 255) / 256), dim3(256), 0, stream, gacc);
    hipLaunchKernelGGL(neo_main_kernel, dim3(nblk), dim3(256), 0, stream,
                       traces, W1h, W1l, b1, W2, b2, schemas, gacc);
    hipLaunchKernelGGL(neo_finalize_kernel, dim3(1), dim3(64), 0, stream,
                       gacc, schemas, usage, out);
}